// Round 7
// baseline (31.965 us; speedup 1.0000x reference)
//
#include <hip/hip_runtime.h>

#define X_DIM 5
#define Y_DIM 2
#define H1 560
#define H2 40
#define GRUH 145
#define G3 435
#define NBLK 37

__device__ __forceinline__ float wave_reduce(float v) {
#pragma unroll
    for (int off = 32; off > 0; off >>= 1)
        v += __shfl_xor(v, off, 64);
    return v;
}
__device__ __forceinline__ float sigmoidf_(float x) { return 1.0f / (1.0f + __expf(-x)); }
__device__ __forceinline__ float dot4(float4 a, float4 b) {
    return fmaf(a.x, b.x, fmaf(a.y, b.y, fmaf(a.z, b.z, a.w * b.w)));
}

// One fused kernel: 37 blocks x 1024 threads (16 waves). Transposed mapping:
// wave w<4 of block b owns GRU element e = w*37+b (h0 then h1); waves w>=4 own
// gh1 row r = (w-4)*37+b. Every block computes l1 redundantly (L2-cheap).
// Grid barrier: RELAXED agent polls (no L2 invalidate; sc1 reaches the
// coherence point) + acquire every 32nd iter as safety + ONE threadfence after
// exit. Tail: non-spinning last-block head (proven in R5/R6).
__global__ __launch_bounds__(1024) void fused_all(
    const float* __restrict__ si, const float* __restrict__ oi,
    const float* __restrict__ dst, const float* __restrict__ dob,
    const float* __restrict__ W1, const float* __restrict__ b1,
    const float* __restrict__ Wih0, const float* __restrict__ Whh0,
    const float* __restrict__ bih0, const float* __restrict__ bhh0,
    const float* __restrict__ Wih1, const float* __restrict__ Whh1,
    const float* __restrict__ bih1, const float* __restrict__ bhh1,
    const float* __restrict__ W2a, const float* __restrict__ b2a,
    const float* __restrict__ W2b, const float* __restrict__ b2b,
    const float* __restrict__ hn,
    unsigned* __restrict__ ctr,          // [0]=barrier, [1]=doneC (memset each call)
    float* __restrict__ h0g, float* __restrict__ gh1g, float* __restrict__ h1g,
    float* __restrict__ out)
{
    __shared__ __align__(16) float sl1[H1];
    __shared__ float sl2h[H2];
    __shared__ unsigned slast;

    const int tid  = threadIdx.x;
    const int w    = tid >> 6;
    const int lane = tid & 63;
    const int b    = blockIdx.x;
    const bool t3  = (lane < 17);    // 145 = 64+64+17
    const bool f3  = (lane < 12);    // 140 float4 = 64+64+12
    const float4 z4 = make_float4(0.f, 0.f, 0.f, 0.f);

    const int eH    = w * NBLK + b;            // element for w<4
    const bool isH0 = (w < 4) && (eH < GRUH);
    const int rG    = (w - 4) * NBLK + b;      // gh1 row for w>=4
    const bool isG  = (w >= 4) && (rG < G3);

    // ---- gh1 waves: fully independent; compute & store immediately ----
    if (isG) {
        const float* rp = Whh1 + rG * GRUH;
        const float wa = rp[lane], wb = rp[lane + 64], wc = t3 ? rp[lane + 128] : 0.f;
        const float ha = hn[GRUH + lane], hb = hn[GRUH + lane + 64],
                    hc = t3 ? hn[GRUH + lane + 128] : 0.f;
        float a = fmaf(wa, ha, fmaf(wb, hb, wc * hc));
        a = wave_reduce(a);
        if (lane == 0) gh1g[rG] = a + bhh1[rG];
    }

    // ---- h0 waves: prefetch weight rows / hn0 / biases (independent of l1) ----
    float4 q00=z4,q01=z4,q02=z4,q10=z4,q11=z4,q12=z4,q20=z4,q21=z4,q22=z4;
    float w00=0,w01=0,w02=0,w10=0,w11=0,w12=0,w20=0,w21=0,w22=0;
    float ha=0,hb=0,hc=0, bi0=0,bi1=0,bi2=0, bh0=0,bh1=0,bh2=0, hne=0;
    if (isH0) {
        const float4* p0 = reinterpret_cast<const float4*>(Wih0 + (eH           ) * H1);
        const float4* p1 = reinterpret_cast<const float4*>(Wih0 + (eH +   GRUH  ) * H1);
        const float4* p2 = reinterpret_cast<const float4*>(Wih0 + (eH + 2 * GRUH) * H1);
        q00 = p0[lane]; q01 = p0[lane + 64]; if (f3) q02 = p0[lane + 128];
        q10 = p1[lane]; q11 = p1[lane + 64]; if (f3) q12 = p1[lane + 128];
        q20 = p2[lane]; q21 = p2[lane + 64]; if (f3) q22 = p2[lane + 128];
        const float* wr0 = Whh0 + (eH           ) * GRUH;
        const float* wr1 = Whh0 + (eH +   GRUH  ) * GRUH;
        const float* wr2 = Whh0 + (eH + 2 * GRUH) * GRUH;
        w00 = wr0[lane]; w01 = wr0[lane + 64]; if (t3) w02 = wr0[lane + 128];
        w10 = wr1[lane]; w11 = wr1[lane + 64]; if (t3) w12 = wr1[lane + 128];
        w20 = wr2[lane]; w21 = wr2[lane + 64]; if (t3) w22 = wr2[lane + 128];
        ha = hn[lane]; hb = hn[lane + 64]; if (t3) hc = hn[lane + 128];
        bi0 = bih0[eH]; bi1 = bih0[eH + GRUH]; bi2 = bih0[eH + 2 * GRUH];
        bh0 = bhh0[eH]; bh1 = bhh0[eH + GRUH]; bh2 = bhh0[eH + 2 * GRUH];
        hne = hn[eH];
    }

    // ---- l1 = relu(W1 @ x + b1): thread-per-row, every block ----
    if (tid < H1) {
        float xx[14];
#pragma unroll
        for (int k = 0; k < 5; ++k) xx[k] = si[k];
        xx[5] = oi[0]; xx[6] = oi[1];
#pragma unroll
        for (int k = 0; k < 5; ++k) xx[7 + k] = dst[k];
        xx[12] = dob[0]; xx[13] = dob[1];
        float a = b1[tid];
        const float* wp = W1 + tid * 14;
#pragma unroll
        for (int k = 0; k < 14; ++k) a = fmaf(wp[k], xx[k], a);
        sl1[tid] = fmaxf(a, 0.0f);
    }
    __syncthreads();

    // ---- h0 compute (prefetched regs x LDS float4) ----
    if (isH0) {
        const float4 s0 = *reinterpret_cast<const float4*>(&sl1[4 * lane]);
        const float4 s1 = *reinterpret_cast<const float4*>(&sl1[4 * (lane + 64)]);
        const float4 s2 = f3 ? *reinterpret_cast<const float4*>(&sl1[4 * (lane + 128)]) : z4;
        float a0 = dot4(q00, s0) + dot4(q01, s1) + dot4(q02, s2);
        float a1 = dot4(q10, s0) + dot4(q11, s1) + dot4(q12, s2);
        float a2 = dot4(q20, s0) + dot4(q21, s1) + dot4(q22, s2);
        float a3 = fmaf(w00, ha, fmaf(w01, hb, w02 * hc));
        float a4 = fmaf(w10, ha, fmaf(w11, hb, w12 * hc));
        float a5 = fmaf(w20, ha, fmaf(w21, hb, w22 * hc));
        a0 = wave_reduce(a0); a1 = wave_reduce(a1); a2 = wave_reduce(a2);
        a3 = wave_reduce(a3); a4 = wave_reduce(a4); a5 = wave_reduce(a5);
        if (lane == 0) {
            const float r = sigmoidf_(a0 + bi0 + a3 + bh0);
            const float z = sigmoidf_(a1 + bi1 + a4 + bh1);
            const float n = tanhf   (a2 + bi2 + r * (a5 + bh2));
            h0g[eH] = (1.0f - z) * n + z * hne;
        }
    }

    // ---- grid barrier: release add; RELAXED poll (+acquire 1/32); one fence ----
    __syncthreads();   // drains this block's global stores (waitcnt before s_barrier)
    if (tid == 0) {
        __hip_atomic_fetch_add(&ctr[0], 1u, __ATOMIC_RELEASE, __HIP_MEMORY_SCOPE_AGENT);
        unsigned it = 0;
        for (;;) {
            const unsigned v = ((++it & 31u) == 0u)
                ? __hip_atomic_load(&ctr[0], __ATOMIC_ACQUIRE, __HIP_MEMORY_SCOPE_AGENT)
                : __hip_atomic_load(&ctr[0], __ATOMIC_RELAXED, __HIP_MEMORY_SCOPE_AGENT);
            if (v >= NBLK) break;
            __builtin_amdgcn_s_sleep(1);
        }
    }
    __syncthreads();

    // ---- stage-C prefetch (immutable inputs; issue BEFORE the fence) ----
    float w0a=0,w0b=0,w0c=0,w1a=0,w1b=0,w1c=0,w2a=0,w2b=0,w2c=0;
    float bj0=0,bj1=0,bj2=0,hn1e=0;
    if (isH0) {
        const float* r0 = Wih1 + (eH           ) * GRUH;
        const float* r1 = Wih1 + (eH +   GRUH  ) * GRUH;
        const float* r2 = Wih1 + (eH + 2 * GRUH) * GRUH;
        w0a = r0[lane]; w0b = r0[lane + 64]; if (t3) w0c = r0[lane + 128];
        w1a = r1[lane]; w1b = r1[lane + 64]; if (t3) w1c = r1[lane + 128];
        w2a = r2[lane]; w2b = r2[lane + 64]; if (t3) w2c = r2[lane + 128];
        bj0 = bih1[eH]; bj1 = bih1[eH + GRUH]; bj2 = bih1[eH + 2 * GRUH];
        hn1e = hn[GRUH + eH];
    }
    __threadfence();   // single acquire-side fence: h0g/gh1g reads below are fresh

    // ---- h1 compute ----
    if (isH0) {
        const float x0 = h0g[lane], x1 = h0g[lane + 64], x2 = t3 ? h0g[lane + 128] : 0.f;
        const float g0 = gh1g[eH], g1 = gh1g[eH + GRUH], g2 = gh1g[eH + 2 * GRUH];
        float c0 = fmaf(w0a, x0, fmaf(w0b, x1, w0c * x2));
        float c1 = fmaf(w1a, x0, fmaf(w1b, x1, w1c * x2));
        float c2 = fmaf(w2a, x0, fmaf(w2b, x1, w2c * x2));
        c0 = wave_reduce(c0); c1 = wave_reduce(c1); c2 = wave_reduce(c2);
        if (lane == 0) {
            const float r = sigmoidf_(c0 + bj0 + g0);
            const float z = sigmoidf_(c1 + bj1 + g1);
            const float n = tanhf   (c2 + bj2 + r * g2);
            h1g[eH] = (1.0f - z) * n + z * hn1e;
        }
    }
    __syncthreads();
    if (tid == 0) {
        const unsigned old =
            __hip_atomic_fetch_add(&ctr[1], 1u, __ATOMIC_ACQ_REL, __HIP_MEMORY_SCOPE_AGENT);
        slast = (old == NBLK - 1u) ? 1u : 0u;
    }
    __syncthreads();
    if (!slast) return;

    // ---- head (last block only) ----
    __threadfence();
    const float ya = h1g[lane], yb = h1g[lane + 64], yc = t3 ? h1g[lane + 128] : 0.f;
#pragma unroll
    for (int rr = 0; rr < 3; ++rr) {
        const int row = w + rr * 16;
        if (row < H2) {
            const float* rp = W2a + row * GRUH;
            float a = fmaf(rp[lane], ya,
                      fmaf(rp[lane + 64], yb, (t3 ? rp[lane + 128] : 0.f) * yc));
            a = wave_reduce(a);
            if (lane == 0) sl2h[row] = fmaxf(a + b2a[row], 0.0f);
        }
    }
    __syncthreads();
    if (tid < X_DIM * Y_DIM) {
        float a = b2b[tid];
        const float* rp = W2b + tid * H2;
#pragma unroll
        for (int k = 0; k < H2; ++k) a = fmaf(rp[k], sl2h[k], a);
        out[tid] = a;
    }
}

extern "C" void kernel_launch(void* const* d_in, const int* in_sizes, int n_in,
                              void* d_out, int out_size, void* d_ws, size_t ws_size,
                              hipStream_t stream) {
    const float* si   = (const float*)d_in[0];
    const float* oi   = (const float*)d_in[1];
    const float* dst  = (const float*)d_in[2];
    const float* dob  = (const float*)d_in[3];
    const float* W1   = (const float*)d_in[4];
    const float* b1   = (const float*)d_in[5];
    const float* Wih0 = (const float*)d_in[6];
    const float* Whh0 = (const float*)d_in[7];
    const float* bih0 = (const float*)d_in[8];
    const float* bhh0 = (const float*)d_in[9];
    const float* Wih1 = (const float*)d_in[10];
    const float* Whh1 = (const float*)d_in[11];
    const float* bih1 = (const float*)d_in[12];
    const float* bhh1 = (const float*)d_in[13];
    const float* W2a  = (const float*)d_in[14];
    const float* b2a  = (const float*)d_in[15];
    const float* W2b  = (const float*)d_in[16];
    const float* b2b  = (const float*)d_in[17];
    const float* hn   = (const float*)d_in[18];

    float* ws = (float*)d_ws;
    unsigned* ctr = (unsigned*)d_ws;   // [0]=barrier, [1]=doneC
    float* h0g  = ws + 64;             // 145 floats
    float* gh1g = ws + 64 + 256;       // 435 floats
    float* h1g  = ws + 64 + 256 + 512; // 145 floats

    hipMemsetAsync(ctr, 0, 2 * sizeof(unsigned), stream);
    hipLaunchKernelGGL(fused_all, dim3(NBLK), dim3(1024), 0, stream,
                       si, oi, dst, dob, W1, b1, Wih0, Whh0, bih0, bhh0,
                       Wih1, Whh1, bih1, bhh1, W2a, b2a, W2b, b2b, hn,
                       ctr, h0g, gh1g, h1g, (float*)d_out);
}

// Round 8
// 16.848 us; speedup vs baseline: 1.8973x; 1.8973x over previous
//
#include <hip/hip_runtime.h>

#define X_DIM 5
#define Y_DIM 2
#define H1 560
#define H2 40
#define GRUH 145
#define G3 435
#define NB_K1 37          // 37*4 waves = 148 >= 145
#define NB_K2 37

__device__ __forceinline__ float wave_reduce(float v) {
#pragma unroll
    for (int off = 32; off > 0; off >>= 1)
        v += __shfl_xor(v, off, 64);
    return v;
}
__device__ __forceinline__ float sigmoidf_(float x) { return 1.0f / (1.0f + __expf(-x)); }
__device__ __forceinline__ float dot4(float4 a, float4 b) {
    return fmaf(a.x, b.x, fmaf(a.y, b.y, fmaf(a.z, b.z, a.w * b.w)));
}

// K1: 37 blocks x 256, wave-per-h0-element only (gh1 moved to K2).
// l1 batched into ONE load epoch (float2 rows); weight rows prefetched to regs
// before the single __syncthreads. Block 0 resets the K2 counter.
__global__ __launch_bounds__(256) void k1_gru0(
    const float* __restrict__ si, const float* __restrict__ oi,
    const float* __restrict__ dst, const float* __restrict__ dob,
    const float* __restrict__ W1, const float* __restrict__ b1,
    const float* __restrict__ Wih0, const float* __restrict__ Whh0,
    const float* __restrict__ bih0, const float* __restrict__ bhh0,
    const float* __restrict__ hn,
    unsigned* __restrict__ ctr,
    float* __restrict__ h0g)
{
    __shared__ __align__(16) float sl1[H1];

    const int tid = threadIdx.x;
    const int wid = tid >> 6, lane = tid & 63;
    const bool t3 = (lane < 17);    // 145 = 64+64+17
    const bool f3 = (lane < 12);    // 140 float4 = 64+64+12
    const float4 z4 = make_float4(0.f, 0.f, 0.f, 0.f);

    if (blockIdx.x == 0 && tid == 0)
        __hip_atomic_store(ctr, 0u, __ATOMIC_RELAXED, __HIP_MEMORY_SCOPE_AGENT);

    const int e   = blockIdx.x * 4 + wid;
    const bool act = (e < GRUH);
    const int ee  = act ? e : (GRUH - 1);

    // ---- prefetch: Wih0 rows (float4), Whh0 rows, hn0, biases ----
    const float4* p0 = reinterpret_cast<const float4*>(Wih0 + (ee           ) * H1);
    const float4* p1 = reinterpret_cast<const float4*>(Wih0 + (ee +   GRUH  ) * H1);
    const float4* p2 = reinterpret_cast<const float4*>(Wih0 + (ee + 2 * GRUH) * H1);
    const float4 q00 = p0[lane], q01 = p0[lane + 64], q02 = f3 ? p0[lane + 128] : z4;
    const float4 q10 = p1[lane], q11 = p1[lane + 64], q12 = f3 ? p1[lane + 128] : z4;
    const float4 q20 = p2[lane], q21 = p2[lane + 64], q22 = f3 ? p2[lane + 128] : z4;
    const float* wr0 = Whh0 + (ee           ) * GRUH;
    const float* wr1 = Whh0 + (ee +   GRUH  ) * GRUH;
    const float* wr2 = Whh0 + (ee + 2 * GRUH) * GRUH;
    const float w00 = wr0[lane], w01 = wr0[lane + 64], w02 = t3 ? wr0[lane + 128] : 0.f;
    const float w10 = wr1[lane], w11 = wr1[lane + 64], w12 = t3 ? wr1[lane + 128] : 0.f;
    const float w20 = wr2[lane], w21 = wr2[lane + 64], w22 = t3 ? wr2[lane + 128] : 0.f;
    const float ha = hn[lane], hb = hn[lane + 64], hc = t3 ? hn[lane + 128] : 0.f;
    const float bi0 = bih0[ee], bi1 = bih0[ee + GRUH], bi2 = bih0[ee + 2 * GRUH];
    const float bh0 = bhh0[ee], bh1 = bhh0[ee + GRUH], bh2 = bhh0[ee + 2 * GRUH];
    const float hne = hn[ee];

    // ---- x into regs (vectorized broadcast) ----
    const float4 s4 = *reinterpret_cast<const float4*>(si);
    const float  s5 = si[4];
    const float2 o2 = *reinterpret_cast<const float2*>(oi);
    const float4 d4 = *reinterpret_cast<const float4*>(dst);
    const float  d5 = dst[4];
    const float2 e2 = *reinterpret_cast<const float2*>(dob);
    float x[14] = { s4.x, s4.y, s4.z, s4.w, s5, o2.x, o2.y,
                    d4.x, d4.y, d4.z, d4.w, d5, e2.x, e2.y };

    // ---- l1 rows j0,j1 (all threads) and j2 (tid<48): ONE load epoch ----
    const int j0 = tid, j1 = tid + 256, j2 = tid + 512;
    const bool has2 = (j2 < H1);
    float2 A[7], B[7], C[7];
    const float2* w1p0 = reinterpret_cast<const float2*>(W1 + j0 * 14);
    const float2* w1p1 = reinterpret_cast<const float2*>(W1 + j1 * 14);
    const float2* w1p2 = reinterpret_cast<const float2*>(W1 + (has2 ? j2 : j0) * 14);
#pragma unroll
    for (int k = 0; k < 7; ++k) { A[k] = w1p0[k]; B[k] = w1p1[k]; C[k] = w1p2[k]; }
    const float bb0 = b1[j0], bb1_ = b1[j1], bb2_ = b1[has2 ? j2 : j0];
    float a0_ = bb0, a1_ = bb1_, a2_ = bb2_;
#pragma unroll
    for (int k = 0; k < 7; ++k) {
        a0_ = fmaf(A[k].x, x[2 * k], fmaf(A[k].y, x[2 * k + 1], a0_));
        a1_ = fmaf(B[k].x, x[2 * k], fmaf(B[k].y, x[2 * k + 1], a1_));
        a2_ = fmaf(C[k].x, x[2 * k], fmaf(C[k].y, x[2 * k + 1], a2_));
    }
    sl1[j0] = fmaxf(a0_, 0.0f);
    sl1[j1] = fmaxf(a1_, 0.0f);
    if (has2) sl1[j2] = fmaxf(a2_, 0.0f);
    __syncthreads();

    // ---- gi0 (prefetched regs x LDS float4) + gh0 (pure regs) ----
    const float4 s0 = *reinterpret_cast<const float4*>(&sl1[4 * lane]);
    const float4 s1 = *reinterpret_cast<const float4*>(&sl1[4 * (lane + 64)]);
    const float4 s2 = f3 ? *reinterpret_cast<const float4*>(&sl1[4 * (lane + 128)]) : z4;
    float a0 = dot4(q00, s0) + dot4(q01, s1) + dot4(q02, s2);
    float a1 = dot4(q10, s0) + dot4(q11, s1) + dot4(q12, s2);
    float a2 = dot4(q20, s0) + dot4(q21, s1) + dot4(q22, s2);
    float a3 = fmaf(w00, ha, fmaf(w01, hb, w02 * hc));
    float a4 = fmaf(w10, ha, fmaf(w11, hb, w12 * hc));
    float a5 = fmaf(w20, ha, fmaf(w21, hb, w22 * hc));
    a0 = wave_reduce(a0); a1 = wave_reduce(a1); a2 = wave_reduce(a2);
    a3 = wave_reduce(a3); a4 = wave_reduce(a4); a5 = wave_reduce(a5);
    if (lane == 0 && act) {
        const float r = sigmoidf_(a0 + bi0 + a3 + bh0);
        const float z = sigmoidf_(a1 + bi1 + a4 + bh1);
        const float n = tanhf   (a2 + bi2 + r * (a5 + bh2));
        h0g[e] = (1.0f - z) * n + z * hne;
    }
}

// K2: 37 blocks x 256. Wave-per-element: 6 dot rows (3 Wih1 over h0g read
// directly + 3 Whh1 over hn1, replacing the old gh1g roundtrip), combine,
// RELEASE store; one fetch_add; all-block W2 prefetch; last block runs head.
__global__ __launch_bounds__(256) void k2_gru1_head(
    const float* __restrict__ Wih1, const float* __restrict__ Whh1,
    const float* __restrict__ bih1, const float* __restrict__ bhh1,
    const float* __restrict__ W2a, const float* __restrict__ b2a,
    const float* __restrict__ W2b, const float* __restrict__ b2b,
    const float* __restrict__ hn,
    const float* __restrict__ h0g,
    unsigned* __restrict__ ctr,
    float* __restrict__ h1g, float* __restrict__ out)
{
    __shared__ float sh1[GRUH];
    __shared__ float sl2h[H2];
    __shared__ unsigned slast;

    const int tid = threadIdx.x;
    const int wid = tid >> 6, lane = tid & 63;
    const bool t3 = (lane < 17);
    const int e   = blockIdx.x * 4 + wid;
    const bool act = (e < GRUH);
    const int ee  = act ? e : (GRUH - 1);

    // ---- prefetch Wih1 + Whh1 rows, biases, hn1, h0 ----
    const float* r0 = Wih1 + (ee           ) * GRUH;
    const float* r1 = Wih1 + (ee +   GRUH  ) * GRUH;
    const float* r2 = Wih1 + (ee + 2 * GRUH) * GRUH;
    const float w0a = r0[lane], w0b = r0[lane + 64], w0c = t3 ? r0[lane + 128] : 0.f;
    const float w1a = r1[lane], w1b = r1[lane + 64], w1c = t3 ? r1[lane + 128] : 0.f;
    const float w2a = r2[lane], w2b = r2[lane + 64], w2c = t3 ? r2[lane + 128] : 0.f;
    const float* u0 = Whh1 + (ee           ) * GRUH;
    const float* u1 = Whh1 + (ee +   GRUH  ) * GRUH;
    const float* u2 = Whh1 + (ee + 2 * GRUH) * GRUH;
    const float v0a = u0[lane], v0b = u0[lane + 64], v0c = t3 ? u0[lane + 128] : 0.f;
    const float v1a = u1[lane], v1b = u1[lane + 64], v1c = t3 ? u1[lane + 128] : 0.f;
    const float v2a = u2[lane], v2b = u2[lane + 64], v2c = t3 ? u2[lane + 128] : 0.f;
    const float bi0 = bih1[ee], bi1 = bih1[ee + GRUH], bi2 = bih1[ee + 2 * GRUH];
    const float bh0 = bhh1[ee], bh1 = bhh1[ee + GRUH], bh2 = bhh1[ee + 2 * GRUH];
    const float ya = hn[GRUH + lane], yb = hn[GRUH + lane + 64],
                yc = t3 ? hn[GRUH + lane + 128] : 0.f;
    const float hn1e = hn[GRUH + ee];
    const float x0 = h0g[lane], x1 = h0g[lane + 64], x2 = t3 ? h0g[lane + 128] : 0.f;

    float c0 = fmaf(w0a, x0, fmaf(w0b, x1, w0c * x2));
    float c1 = fmaf(w1a, x0, fmaf(w1b, x1, w1c * x2));
    float c2 = fmaf(w2a, x0, fmaf(w2b, x1, w2c * x2));
    float d0 = fmaf(v0a, ya, fmaf(v0b, yb, v0c * yc));
    float d1 = fmaf(v1a, ya, fmaf(v1b, yb, v1c * yc));
    float d2 = fmaf(v2a, ya, fmaf(v2b, yb, v2c * yc));
    c0 = wave_reduce(c0); c1 = wave_reduce(c1); c2 = wave_reduce(c2);
    d0 = wave_reduce(d0); d1 = wave_reduce(d1); d2 = wave_reduce(d2);
    if (lane == 0 && act) {
        const float r = sigmoidf_(c0 + bi0 + d0 + bh0);
        const float z = sigmoidf_(c1 + bi1 + d1 + bh1);
        const float n = tanhf   (c2 + bi2 + r * (d2 + bh2));
        const float v = (1.0f - z) * n + z * hn1e;
        __hip_atomic_store(&h1g[e], v, __ATOMIC_RELEASE, __HIP_MEMORY_SCOPE_AGENT);
    }
    __syncthreads();
    if (tid == 0) {
        const unsigned old =
            __hip_atomic_fetch_add(ctr, 1u, __ATOMIC_ACQ_REL, __HIP_MEMORY_SCOPE_AGENT);
        slast = (old == NB_K2 - 1u) ? 1u : 0u;
    }

    // ---- head-weight prefetch (in flight while slast resolves) ----
    float wa[10][3];
    const int rbase = wid * 10;
#pragma unroll
    for (int m = 0; m < 10; ++m) {
        const float* rp = W2a + (rbase + m) * GRUH;
        wa[m][0] = rp[lane];
        wa[m][1] = rp[lane + 64];
        wa[m][2] = t3 ? rp[lane + 128] : 0.f;
    }
    float ba[10];
#pragma unroll
    for (int m = 0; m < 10; ++m) ba[m] = b2a[rbase + m];
    float wb2[H2], bb2 = 0.f;
    if (tid < X_DIM * Y_DIM) {
        const float* rp = W2b + tid * H2;
#pragma unroll
        for (int k = 0; k < H2; ++k) wb2[k] = rp[k];
        bb2 = b2b[tid];
    }

    __syncthreads();
    if (!slast) return;

    // ---- last block only: stage h1 (acquire) and run the head ----
    for (int j = tid; j < GRUH; j += 256)
        sh1[j] = __hip_atomic_load(&h1g[j], __ATOMIC_ACQUIRE, __HIP_MEMORY_SCOPE_AGENT);
    __syncthreads();

    const float za = sh1[lane], zb = sh1[lane + 64], zc = t3 ? sh1[lane + 128] : 0.f;
#pragma unroll
    for (int m = 0; m < 10; ++m) {
        float a = fmaf(wa[m][0], za, fmaf(wa[m][1], zb, wa[m][2] * zc));
        a = wave_reduce(a);
        if (lane == 0) sl2h[rbase + m] = fmaxf(a + ba[m], 0.0f);
    }
    __syncthreads();
    if (tid < X_DIM * Y_DIM) {
        float a = bb2;
#pragma unroll
        for (int k = 0; k < H2; ++k) a = fmaf(wb2[k], sl2h[k], a);
        out[tid] = a;
    }
}

extern "C" void kernel_launch(void* const* d_in, const int* in_sizes, int n_in,
                              void* d_out, int out_size, void* d_ws, size_t ws_size,
                              hipStream_t stream) {
    const float* si   = (const float*)d_in[0];
    const float* oi   = (const float*)d_in[1];
    const float* dst  = (const float*)d_in[2];
    const float* dob  = (const float*)d_in[3];
    const float* W1   = (const float*)d_in[4];
    const float* b1   = (const float*)d_in[5];
    const float* Wih0 = (const float*)d_in[6];
    const float* Whh0 = (const float*)d_in[7];
    const float* bih0 = (const float*)d_in[8];
    const float* bhh0 = (const float*)d_in[9];
    const float* Wih1 = (const float*)d_in[10];
    const float* Whh1 = (const float*)d_in[11];
    const float* bih1 = (const float*)d_in[12];
    const float* bhh1 = (const float*)d_in[13];
    const float* W2a  = (const float*)d_in[14];
    const float* b2a  = (const float*)d_in[15];
    const float* W2b  = (const float*)d_in[16];
    const float* b2b  = (const float*)d_in[17];
    const float* hn   = (const float*)d_in[18];

    float* ws = (float*)d_ws;
    unsigned* ctr = (unsigned*)d_ws;   // 1 cache line
    float* h0g = ws + 64;              // 145 floats
    float* h1g = ws + 64 + 256;        // 145 floats

    hipLaunchKernelGGL(k1_gru0, dim3(NB_K1), dim3(256), 0, stream,
                       si, oi, dst, dob, W1, b1, Wih0, Whh0, bih0, bhh0,
                       hn, ctr, h0g);
    hipLaunchKernelGGL(k2_gru1_head, dim3(NB_K2), dim3(256), 0, stream,
                       Wih1, Whh1, bih1, bhh1, W2a, b2a, W2b, b2b, hn,
                       h0g, ctr, h1g, (float*)d_out);
}